// Round 5
// baseline (200.803 us; speedup 1.0000x reference)
//
#include <hip/hip_runtime.h>
#include <math.h>

#define NTOK 8192
#define DD   2048
#define EE   64
#define TSTRIP 8             // tokens per block (half an MFMA m-tile; rows 8-15 garbage)
#define NCH 16               // chunks per K-half (64 d each)
#define PROB_N (NTOK*2)
#define AROW 136             // 128 feats + 8 pad; 272B rows, 16B aligned
// F layout: [plane:2][ck:128][nt:4][lane:64][j:8] fp16 = 1 MB
#define F_PSTRIDE (128*4*64*8)

typedef _Float16 f16x8 __attribute__((ext_vector_type(8)));
typedef _Float16 f16x4 __attribute__((ext_vector_type(4)));
typedef float    f32x4 __attribute__((ext_vector_type(4)));

// fast branchless atan2 (Cephes reduction + deg-7 odd minimax), ~3e-7 abs
__device__ __forceinline__ float fast_atan2f(float y, float x) {
    const float ax = __builtin_fabsf(x), ay = __builtin_fabsf(y);
    const float hi = fmaxf(ax, ay), lo = fminf(ax, ay);
    const bool  big = lo > 0.4142135679721832f * hi;       // tan(pi/8)
    const float num = big ? (lo - hi) : lo;
    const float den = big ? (lo + hi) : hi;
    float rc = __builtin_amdgcn_rcpf(den);
    rc = rc * fmaf(-den, rc, 2.0f);                        // 1 NR step
    const float z  = num * rc;
    const float z2 = z * z;
    float p = fmaf(z2, 8.05374449538e-2f, -1.38776856032e-1f);
    p = fmaf(z2, p, 1.99777106478e-1f);
    p = fmaf(z2, p, -3.33329491539e-1f);
    float r = fmaf(z * z2, p, z);
    r = r + (big ? 0.78539816339744830962f : 0.0f);
    r = (ay > ax) ? (1.57079632679489661923f - r) : r;
    r = (x < 0.0f) ? (3.14159265358979323846f - r) : r;
    return copysignf(r, y);
}

// fp16 2-split with scaled low plane: x ~= h1 + h2s*2^-11, err ~2^-24|x|
__device__ __forceinline__ void fsplit2(float x, _Float16& h1, _Float16& h2s) {
    const _Float16 a = (_Float16)x;                 // RNE, 11 bits
    h1 = a;
    h2s = (_Float16)((x - (float)a) * 2048.0f);     // next ~12 bits, normal-scaled
}

// Kernel 0: split W [4096][64] fp32 -> F fragment-order fp16 (2 planes, 1 MB)
__global__ __launch_bounds__(256) void wsplit(const float* __restrict__ W,
                                              _Float16* __restrict__ F) {
    const int g  = blockIdx.x * 256 + threadIdx.x;   // 32768 threads
    const int e  = g & 63;
    const int q  = g >> 6;          // 0..511
    const int d0 = q * 4;
    const int nt = e >> 4;
    const int lane = ((d0 & 31) >> 3) * 16 + (e & 15);
    const int j0 = d0 & 7;          // 0 or 4
    const int cka = 2 * (d0 >> 5);  // amp kstep; phase kstep = cka+1

    f16x4 a1, a2, p1, p2;
    #pragma unroll
    for (int i = 0; i < 4; ++i) {
        _Float16 h, l;
        fsplit2(W[(size_t)(d0 + i) * EE + e], h, l);      a1[i] = h; a2[i] = l;
        fsplit2(W[(size_t)(DD + d0 + i) * EE + e], h, l); p1[i] = h; p2[i] = l;
    }
    *(f16x4*)&F[((size_t)(0 * 128 + cka)     * 4 + nt) * 512 + lane * 8 + j0] = a1;
    *(f16x4*)&F[((size_t)(1 * 128 + cka)     * 4 + nt) * 512 + lane * 8 + j0] = a2;
    *(f16x4*)&F[((size_t)(0 * 128 + cka + 1) * 4 + nt) * 512 + lane * 8 + j0] = p1;
    *(f16x4*)&F[((size_t)(1 * 128 + cka + 1) * 4 + nt) * 512 + lane * 8 + j0] = p2;
}

// Kernel 1: R0 compiler-managed structure (no asm pipeline -- R4's asm +
// 64-VGPR cap spilled in-flight load destinations and memory-faulted),
// TSTRIP=8 -> grid 1024 = 4 blocks/CU, 32 waves/CU: the TLP experiment.
// A declared 16 rows, rows 8-15 never staged; MFMA output rows 8-15 are
// garbage, discarded by the fq<2 guard. Waves 0-3 stage x (256 threads =
// 2 kh x 8 tok x 16 f4); waves 4-7 only stream B.
__global__ __launch_bounds__(512, 8) void gemm_topk(
    const float* __restrict__ xr, const float* __restrict__ xi,
    const _Float16* __restrict__ F, const float* __restrict__ bias,
    float* __restrict__ out)
{
    __shared__ __align__(16) _Float16 A[2][2][2][16][AROW];  // 34 KB (rows 8-15 unused)
    __shared__ float scoreH[2][TSTRIP][EE];                   // 4 KB

    const int tid = threadIdx.x;
    const int t0  = blockIdx.x * TSTRIP;
    // compute roles
    const int wv = tid >> 6, lane = tid & 63;
    const int nt = wv & 3, kh = wv >> 2;
    const int fm = lane & 15, fq = lane >> 4;
    // staging roles (tid < 256 only): 2 kh x 8 tok x 16 f4
    const int kh_s  = (tid >> 7) & 1;
    const int tok_s = (tid >> 4) & 7;
    const int f4    = tid & 15;
    const bool stager = (wv < 4);

    const float bv = bias[lane];

    const float* prx = xr + (size_t)(t0 + tok_s) * DD + kh_s * 1024 + f4 * 4;
    const float* pix = xi + (size_t)(t0 + tok_s) * DD + kh_s * 1024 + f4 * 4;
    const int posa = 64 * (f4 >> 3) + (f4 & 7) * 4;   // amp slot; phase = +32

    auto sprocess = [&](float4 vr, float4 vi, int buf) {
        const float ar[4] = {vr.x, vr.y, vr.z, vr.w};
        const float ai[4] = {vi.x, vi.y, vi.z, vi.w};
        f16x4 a1, a2, p1, p2;
        #pragma unroll
        for (int i = 0; i < 4; ++i) {
            const float amp = __builtin_amdgcn_sqrtf(fmaf(ar[i], ar[i], ai[i] * ai[i]));
            const float ph  = fast_atan2f(ai[i], ar[i]);
            _Float16 h, l;
            fsplit2(amp, h, l); a1[i] = h; a2[i] = l;
            fsplit2(ph,  h, l); p1[i] = h; p2[i] = l;
        }
        *(f16x4*)&A[buf][kh_s][0][tok_s][posa]      = a1;
        *(f16x4*)&A[buf][kh_s][1][tok_s][posa]      = a2;
        *(f16x4*)&A[buf][kh_s][0][tok_s][posa + 32] = p1;
        *(f16x4*)&A[buf][kh_s][1][tok_s][posa + 32] = p2;
    };

    f32x4 accH = (f32x4){0.f, 0.f, 0.f, 0.f};
    f32x4 accL = (f32x4){0.f, 0.f, 0.f, 0.f};

    // prologue: stage chunk 0
    if (stager) sprocess(*(const float4*)prx, *(const float4*)pix, 0);
    __syncthreads();

    for (int c = 0; c < NCH; ++c) {
        const int buf = c & 1;
        // issue next chunk's x first (longest latency, covered by B+MFMA below)
        float4 nvr, nvi;
        if (stager && c + 1 < NCH) {
            nvr = *(const float4*)(prx + (c + 1) * 64);
            nvi = *(const float4*)(pix + (c + 1) * 64);
        }
        // B fragments: 4 cksteps x 2 planes, contiguous 1KB wave loads
        const int ck0 = kh * 64 + c * 4;
        const _Float16* b1p = F + ((size_t)ck0 * 4 + nt) * 512 + lane * 8;
        const _Float16* b2p = b1p + F_PSTRIDE;
        f16x8 b1[4], b2[4], a1[4], a2[4];
        #pragma unroll
        for (int j = 0; j < 4; ++j) {
            b1[j] = *(const f16x8*)(b1p + j * 2048);
            b2[j] = *(const f16x8*)(b2p + j * 2048);
        }
        #pragma unroll
        for (int j = 0; j < 4; ++j) {
            a1[j] = *(const f16x8*)&A[buf][kh][0][fm][j * 32 + fq * 8];
            a2[j] = *(const f16x8*)&A[buf][kh][1][fm][j * 32 + fq * 8];
        }
        #pragma unroll
        for (int j = 0; j < 4; ++j) {
            accH = __builtin_amdgcn_mfma_f32_16x16x32_f16(a1[j], b1[j], accH, 0, 0, 0);
            accL = __builtin_amdgcn_mfma_f32_16x16x32_f16(a1[j], b2[j], accL, 0, 0, 0);
            accL = __builtin_amdgcn_mfma_f32_16x16x32_f16(a2[j], b1[j], accL, 0, 0, 0);
        }
        if (stager && c + 1 < NCH) sprocess(nvr, nvi, buf ^ 1);
        __syncthreads();
    }

    // D layout: col=lane&15, row=(lane>>4)*4+reg [m89]; rows 8-15 garbage -> skip
    if (fq < 2) {
        #pragma unroll
        for (int r = 0; r < 4; ++r)
            scoreH[kh][fq * 4 + r][nt * 16 + fm] = fmaf(accL[r], 4.8828125e-4f, accH[r]);
    }
    __syncthreads();

    // exact top-2 (tie-break lower index, matching lax.top_k); 1 token/wave
    {
        const int tok = wv;
        float v1 = scoreH[0][tok][lane] + scoreH[1][tok][lane] + bv;
        float v2 = -INFINITY;
        int   i1 = lane, i2 = 64;
        #pragma unroll
        for (int off = 1; off < 64; off <<= 1) {
            const float ov1 = __shfl_xor(v1, off, 64);
            const int   oi1 = __shfl_xor(i1, off, 64);
            const float ov2 = __shfl_xor(v2, off, 64);
            const int   oi2 = __shfl_xor(i2, off, 64);
            const bool b1 = (ov1 > v1) || (ov1 == v1 && oi1 < i1);
            const float n1 = b1 ? ov1 : v1;  const int ni1 = b1 ? oi1 : i1;
            const float c1 = b1 ? v1  : ov1; const int ci1 = b1 ? i1  : oi1;
            const float c2 = b1 ? ov2 : v2;  const int ci2 = b1 ? oi2 : i2;
            const bool b2 = (c1 > c2) || (c1 == c2 && ci1 < ci2);
            v1 = n1; i1 = ni1;
            v2 = b2 ? c1 : c2; i2 = b2 ? ci1 : ci2;
        }
        if (lane == 0) {
            const int t = t0 + tok;
            const float z  = expf(v2 - v1);
            const float p1 = 1.0f / (1.0f + z);
            const float p2 = z / (1.0f + z);
            out[(size_t)t * 2 + 0] = p1;
            out[(size_t)t * 2 + 1] = p2;
            out[PROB_N + (size_t)t * 2 + 0] = (float)i1;
            out[PROB_N + (size_t)t * 2 + 1] = (float)i2;
        }
    }
}

extern "C" void kernel_launch(void* const* d_in, const int* in_sizes, int n_in,
                              void* d_out, int out_size, void* d_ws, size_t ws_size,
                              hipStream_t stream) {
    const float* xr = (const float*)d_in[0];
    const float* xi = (const float*)d_in[1];
    const float* W  = (const float*)d_in[2];
    const float* b  = (const float*)d_in[3];
    float* out = (float*)d_out;
    _Float16* F = (_Float16*)d_ws;   // 1 MB swizzled 2-plane fp16 W

    wsplit<<<128, 256, 0, stream>>>(W, F);
    gemm_topk<<<NTOK / TSTRIP, 512, 0, stream>>>(xr, xi, F, b, out);
}

// Round 6
// 175.225 us; speedup vs baseline: 1.1460x; 1.1460x over previous
//
#include <hip/hip_runtime.h>
#include <math.h>

#define NTOK 8192
#define DD   2048
#define EE   64
#define TSTRIP 16            // tokens per block (one MFMA m-tile)
#define PROB_N (NTOK*2)
// F layout: [plane:2][ck:128][nt:4][lane:64][j:8] fp16 = 1 MB
#define F_PSTRIDE (128*4*64*8)

typedef _Float16 f16x8 __attribute__((ext_vector_type(8)));
typedef _Float16 f16x4 __attribute__((ext_vector_type(4)));
typedef float    f32x4 __attribute__((ext_vector_type(4)));

// fast branchless atan2 (Cephes reduction + deg-7 odd minimax), ~3e-7 abs
__device__ __forceinline__ float fast_atan2f(float y, float x) {
    const float ax = __builtin_fabsf(x), ay = __builtin_fabsf(y);
    const float hi = fmaxf(ax, ay), lo = fminf(ax, ay);
    const bool  big = lo > 0.4142135679721832f * hi;       // tan(pi/8)
    const float num = big ? (lo - hi) : lo;
    const float den = big ? (lo + hi) : hi;
    float rc = __builtin_amdgcn_rcpf(den);
    rc = rc * fmaf(-den, rc, 2.0f);                        // 1 NR step
    const float z  = num * rc;
    const float z2 = z * z;
    float p = fmaf(z2, 8.05374449538e-2f, -1.38776856032e-1f);
    p = fmaf(z2, p, 1.99777106478e-1f);
    p = fmaf(z2, p, -3.33329491539e-1f);
    float r = fmaf(z * z2, p, z);
    r = r + (big ? 0.78539816339744830962f : 0.0f);
    r = (ay > ax) ? (1.57079632679489661923f - r) : r;
    r = (x < 0.0f) ? (3.14159265358979323846f - r) : r;
    return copysignf(r, y);
}

// fp16 2-split with scaled low plane: x ~= h1 + h2s*2^-11, err ~2^-24|x|
__device__ __forceinline__ void fsplit2(float x, _Float16& h1, _Float16& h2s) {
    const _Float16 a = (_Float16)x;                 // RNE, 11 bits
    h1 = a;
    h2s = (_Float16)((x - (float)a) * 2048.0f);     // next ~12 bits, normal-scaled
}

// Kernel 0: split W [4096][64] fp32 -> F fragment-order fp16 (2 planes, 1 MB)
// ck = 2*(d>>5) holds amp of a 32-d group; ck+1 holds phase of the same d.
__global__ __launch_bounds__(256) void wsplit(const float* __restrict__ W,
                                              _Float16* __restrict__ F) {
    const int g  = blockIdx.x * 256 + threadIdx.x;   // 32768 threads
    const int e  = g & 63;
    const int q  = g >> 6;          // 0..511
    const int d0 = q * 4;
    const int nt = e >> 4;
    const int lane = ((d0 & 31) >> 3) * 16 + (e & 15);
    const int j0 = d0 & 7;          // 0 or 4
    const int cka = 2 * (d0 >> 5);  // amp kstep; phase kstep = cka+1

    f16x4 a1, a2, p1, p2;
    #pragma unroll
    for (int i = 0; i < 4; ++i) {
        _Float16 h, l;
        fsplit2(W[(size_t)(d0 + i) * EE + e], h, l);      a1[i] = h; a2[i] = l;
        fsplit2(W[(size_t)(DD + d0 + i) * EE + e], h, l); p1[i] = h; p2[i] = l;
    }
    *(f16x4*)&F[((size_t)(0 * 128 + cka)     * 4 + nt) * 512 + lane * 8 + j0] = a1;
    *(f16x4*)&F[((size_t)(1 * 128 + cka)     * 4 + nt) * 512 + lane * 8 + j0] = a2;
    *(f16x4*)&F[((size_t)(0 * 128 + cka + 1) * 4 + nt) * 512 + lane * 8 + j0] = p1;
    *(f16x4*)&F[((size_t)(1 * 128 + cka + 1) * 4 + nt) * 512 + lane * 8 + j0] = p2;
}

// Kernel 1: BARRIER-FREE independent-wave streaming (R0-R5 post-mortem:
// chunk-synchronous block structure convoys; every pipe <=30% at any
// occupancy). Each wave: 16 tokens x 256-d K-slice. Lane (fm,fq) loads
// x[t0+fm][p*32+fq*8+0..7] = exactly its A-fragment elements, transforms
// amp/phase IN REGISTERS (no LDS staging, no sharing), and MFMAs against
// all 4 expert tiles (transform done once per element). One barrier total.
__global__ __launch_bounds__(512) void gemm_topk(
    const float* __restrict__ xr, const float* __restrict__ xi,
    const _Float16* __restrict__ F, const float* __restrict__ bias,
    float* __restrict__ out)
{
    __shared__ float scoreP[8][TSTRIP][EE];   // 32 KB partial scores per K-slice

    const int tid = threadIdx.x;
    const int t0  = blockIdx.x * TSTRIP;
    const int wv = tid >> 6, lane = tid & 63;  // wv = K-slice 0..7
    const int fm = lane & 15, fq = lane >> 4;

    // this lane's x stream: row t0+fm, d = wv*256 + p*32 + fq*8 + (0..7)
    const float* prx = xr + (size_t)(t0 + fm) * DD + wv * 256 + fq * 8;
    const float* pix = xi + (size_t)(t0 + fm) * DD + wv * 256 + fq * 8;

    f32x4 accH[4], accL[4];                    // per expert-tile nt
    #pragma unroll
    for (int nt = 0; nt < 4; ++nt) {
        accH[nt] = (f32x4){0.f, 0.f, 0.f, 0.f};
        accL[nt] = (f32x4){0.f, 0.f, 0.f, 0.f};
    }

    #pragma unroll 2
    for (int p = 0; p < 8; ++p) {
        // 8 complex elements for this lane's A-fragment (4x float4)
        const float4 r0 = *(const float4*)(prx + p * 32);
        const float4 r1 = *(const float4*)(prx + p * 32 + 4);
        const float4 i0 = *(const float4*)(pix + p * 32);
        const float4 i1 = *(const float4*)(pix + p * 32 + 4);

        // transform -> amp/phase fragments (hi + scaled-lo planes), in regs
        f16x8 a1, a2, q1, q2;
        #pragma unroll
        for (int h = 0; h < 2; ++h) {
            const float4 vr = h ? r1 : r0;
            const float4 vi = h ? i1 : i0;
            const float ar[4] = {vr.x, vr.y, vr.z, vr.w};
            const float ai[4] = {vi.x, vi.y, vi.z, vi.w};
            #pragma unroll
            for (int i = 0; i < 4; ++i) {
                const float amp = __builtin_amdgcn_sqrtf(fmaf(ar[i], ar[i], ai[i] * ai[i]));
                const float ph  = fast_atan2f(ai[i], ar[i]);
                _Float16 hh, ll;
                fsplit2(amp, hh, ll); a1[h * 4 + i] = hh; a2[h * 4 + i] = ll;
                fsplit2(ph,  hh, ll); q1[h * 4 + i] = hh; q2[h * 4 + i] = ll;
            }
        }

        // B fragments: amp ck = 2*(global d-group), phase ck = +1 (-> +2048 elems)
        const int ck = (wv * 8 + p) * 2;
        const _Float16* bp = F + ((size_t)ck * 4) * 512 + lane * 8;
        #pragma unroll
        for (int nt = 0; nt < 4; ++nt) {
            const _Float16* qp = bp + nt * 512;
            const f16x8 b1a = *(const f16x8*)(qp);
            const f16x8 b2a = *(const f16x8*)(qp + F_PSTRIDE);
            const f16x8 b1p = *(const f16x8*)(qp + 2048);
            const f16x8 b2p = *(const f16x8*)(qp + 2048 + F_PSTRIDE);
            accH[nt] = __builtin_amdgcn_mfma_f32_16x16x32_f16(a1, b1a, accH[nt], 0, 0, 0);
            accL[nt] = __builtin_amdgcn_mfma_f32_16x16x32_f16(a1, b2a, accL[nt], 0, 0, 0);
            accL[nt] = __builtin_amdgcn_mfma_f32_16x16x32_f16(a2, b1a, accL[nt], 0, 0, 0);
            accH[nt] = __builtin_amdgcn_mfma_f32_16x16x32_f16(q1, b1p, accH[nt], 0, 0, 0);
            accL[nt] = __builtin_amdgcn_mfma_f32_16x16x32_f16(q1, b2p, accL[nt], 0, 0, 0);
            accL[nt] = __builtin_amdgcn_mfma_f32_16x16x32_f16(q2, b1p, accL[nt], 0, 0, 0);
        }
    }

    // write K-slice partials. D layout: col=lane&15, row=(lane>>4)*4+reg [m89]
    #pragma unroll
    for (int nt = 0; nt < 4; ++nt)
        #pragma unroll
        for (int r = 0; r < 4; ++r)
            scoreP[wv][fq * 4 + r][nt * 16 + fm] =
                fmaf(accL[nt][r], 4.8828125e-4f, accH[nt][r]);
    __syncthreads();   // the ONLY block-wide sync

    // exact top-2 (tie-break lower index, matching lax.top_k); 2 tokens/wave
    const float bv = bias[lane];
    #pragma unroll
    for (int rep = 0; rep < 2; ++rep) {
        const int tok = wv * 2 + rep;
        float v1 = bv;
        #pragma unroll
        for (int kq = 0; kq < 8; ++kq) v1 += scoreP[kq][tok][lane];
        float v2 = -INFINITY;
        int   i1 = lane, i2 = 64;
        #pragma unroll
        for (int off = 1; off < 64; off <<= 1) {
            const float ov1 = __shfl_xor(v1, off, 64);
            const int   oi1 = __shfl_xor(i1, off, 64);
            const float ov2 = __shfl_xor(v2, off, 64);
            const int   oi2 = __shfl_xor(i2, off, 64);
            const bool b1 = (ov1 > v1) || (ov1 == v1 && oi1 < i1);
            const float n1 = b1 ? ov1 : v1;  const int ni1 = b1 ? oi1 : i1;
            const float c1 = b1 ? v1  : ov1; const int ci1 = b1 ? i1  : oi1;
            const float c2 = b1 ? ov2 : v2;  const int ci2 = b1 ? oi2 : i2;
            const bool b2 = (c1 > c2) || (c1 == c2 && ci1 < ci2);
            v1 = n1; i1 = ni1;
            v2 = b2 ? c1 : c2; i2 = b2 ? ci1 : ci2;
        }
        if (lane == 0) {
            const int t = t0 + tok;
            const float z  = expf(v2 - v1);
            const float p1 = 1.0f / (1.0f + z);
            const float p2 = z / (1.0f + z);
            out[(size_t)t * 2 + 0] = p1;
            out[(size_t)t * 2 + 1] = p2;
            out[PROB_N + (size_t)t * 2 + 0] = (float)i1;
            out[PROB_N + (size_t)t * 2 + 1] = (float)i2;
        }
    }
}

extern "C" void kernel_launch(void* const* d_in, const int* in_sizes, int n_in,
                              void* d_out, int out_size, void* d_ws, size_t ws_size,
                              hipStream_t stream) {
    const float* xr = (const float*)d_in[0];
    const float* xi = (const float*)d_in[1];
    const float* W  = (const float*)d_in[2];
    const float* b  = (const float*)d_in[3];
    float* out = (float*)d_out;
    _Float16* F = (_Float16*)d_ws;   // 1 MB swizzled 2-plane fp16 W

    wsplit<<<128, 256, 0, stream>>>(W, F);
    gemm_topk<<<NTOK / TSTRIP, 512, 0, stream>>>(xr, xi, F, b, out);
}

// Round 7
// 173.707 us; speedup vs baseline: 1.1560x; 1.0087x over previous
//
#include <hip/hip_runtime.h>
#include <math.h>

#define NTOK 8192
#define DD   2048
#define EE   64
#define TSTRIP 16            // tokens per block (one MFMA m-tile)
#define PROB_N (NTOK*2)
// F layout: [plane:2][ck:128][nt:4][lane:64][j:8] fp16 = 1 MB
#define F_PSTRIDE (128*4*64*8)

typedef _Float16 f16x8 __attribute__((ext_vector_type(8)));
typedef _Float16 f16x4 __attribute__((ext_vector_type(4)));
typedef float    f32x4 __attribute__((ext_vector_type(4)));

// pinned-issue loads: volatile asm = strict program-order issue, and the
// destination VGPR stays allocated from issue to consumption.
__device__ __forceinline__ f16x8 gload_f16x8(const _Float16* p) {
    f16x8 r;
    asm volatile("global_load_dwordx4 %0, %1, off" : "=v"(r) : "v"(p));
    return r;
}
__device__ __forceinline__ f32x4 gload_f32x4(const float* p) {
    f32x4 r;
    asm volatile("global_load_dwordx4 %0, %1, off" : "=v"(r) : "v"(p));
    return r;
}
// counted wait + full scheduling fence (rule #18: consumers -- MFMA and the
// transform VALU reading asm outputs -- must not be scheduled above this)
#define VMWAIT(n) do { \
    asm volatile("s_waitcnt vmcnt(" #n ")" ::: "memory"); \
    __builtin_amdgcn_sched_barrier(0); \
} while (0)

// fast branchless atan2 (Cephes reduction + deg-7 odd minimax), ~3e-7 abs
__device__ __forceinline__ float fast_atan2f(float y, float x) {
    const float ax = __builtin_fabsf(x), ay = __builtin_fabsf(y);
    const float hi = fmaxf(ax, ay), lo = fminf(ax, ay);
    const bool  big = lo > 0.4142135679721832f * hi;       // tan(pi/8)
    const float num = big ? (lo - hi) : lo;
    const float den = big ? (lo + hi) : hi;
    float rc = __builtin_amdgcn_rcpf(den);
    rc = rc * fmaf(-den, rc, 2.0f);                        // 1 NR step
    const float z  = num * rc;
    const float z2 = z * z;
    float p = fmaf(z2, 8.05374449538e-2f, -1.38776856032e-1f);
    p = fmaf(z2, p, 1.99777106478e-1f);
    p = fmaf(z2, p, -3.33329491539e-1f);
    float r = fmaf(z * z2, p, z);
    r = r + (big ? 0.78539816339744830962f : 0.0f);
    r = (ay > ax) ? (1.57079632679489661923f - r) : r;
    r = (x < 0.0f) ? (3.14159265358979323846f - r) : r;
    return copysignf(r, y);
}

// fp16 2-split with scaled low plane: x ~= h1 + h2s*2^-11, err ~2^-24|x|
__device__ __forceinline__ void fsplit2(float x, _Float16& h1, _Float16& h2s) {
    const _Float16 a = (_Float16)x;                 // RNE, 11 bits
    h1 = a;
    h2s = (_Float16)((x - (float)a) * 2048.0f);     // next ~12 bits, normal-scaled
}

// Kernel 0: split W [4096][64] fp32 -> F fragment-order fp16 (2 planes, 1 MB)
__global__ __launch_bounds__(256) void wsplit(const float* __restrict__ W,
                                              _Float16* __restrict__ F) {
    const int g  = blockIdx.x * 256 + threadIdx.x;   // 32768 threads
    const int e  = g & 63;
    const int q  = g >> 6;          // 0..511
    const int d0 = q * 4;
    const int nt = e >> 4;
    const int lane = ((d0 & 31) >> 3) * 16 + (e & 15);
    const int j0 = d0 & 7;          // 0 or 4
    const int cka = 2 * (d0 >> 5);  // amp kstep; phase kstep = cka+1

    f16x4 a1, a2, p1, p2;
    #pragma unroll
    for (int i = 0; i < 4; ++i) {
        _Float16 h, l;
        fsplit2(W[(size_t)(d0 + i) * EE + e], h, l);      a1[i] = h; a2[i] = l;
        fsplit2(W[(size_t)(DD + d0 + i) * EE + e], h, l); p1[i] = h; p2[i] = l;
    }
    *(f16x4*)&F[((size_t)(0 * 128 + cka)     * 4 + nt) * 512 + lane * 8 + j0] = a1;
    *(f16x4*)&F[((size_t)(1 * 128 + cka)     * 4 + nt) * 512 + lane * 8 + j0] = a2;
    *(f16x4*)&F[((size_t)(0 * 128 + cka + 1) * 4 + nt) * 512 + lane * 8 + j0] = p1;
    *(f16x4*)&F[((size_t)(1 * 128 + cka + 1) * 4 + nt) * 512 + lane * 8 + j0] = p2;
}

// Kernel 1: R6's barrier-free independent-wave structure + asm-pinned
// 1-iter software pipeline (the MLP fix). Steady-state 24-36 loads in
// flight per wave; vmcnt never drains mid-loop. No __launch_bounds__
// wave cap (R4 lesson: caps + asm pipelines spill in-flight load dests).
__global__ __launch_bounds__(512) void gemm_topk(
    const float* __restrict__ xr, const float* __restrict__ xi,
    const _Float16* __restrict__ F, const float* __restrict__ bias,
    float* __restrict__ out)
{
    __shared__ float scoreP[8][TSTRIP][EE];   // 32 KB partial scores per K-slice

    const int tid = threadIdx.x;
    const int t0  = blockIdx.x * TSTRIP;
    const int wv = tid >> 6, lane = tid & 63;  // wv = K-slice 0..7
    const int fm = lane & 15, fq = lane >> 4;

    // this lane's x stream: row t0+fm, d = wv*256 + p*32 + fq*8 + (0..7)
    const float* prx = xr + (size_t)(t0 + fm) * DD + wv * 256 + fq * 8;
    const float* pix = xi + (size_t)(t0 + fm) * DD + wv * 256 + fq * 8;
    // B base for p=0 (chunk p at +p*4096 elements)
    const _Float16* bp0 = F + (size_t)wv * 32768 + lane * 8;

    f32x4 accH[4], accL[4];
    #pragma unroll
    for (int nt = 0; nt < 4; ++nt) {
        accH[nt] = (f32x4){0.f, 0.f, 0.f, 0.f};
        accL[nt] = (f32x4){0.f, 0.f, 0.f, 0.f};
    }

    // pipeline register state; ALL indices compile-time static (full unroll)
    f32x4 xv[2][4];     // [slot][r0,r1,i0,i1]      : 32 VGPR
    f16x8 bb[2][16];    // [slot][nt*4 + {1a,2a,1p,2p}] : 128 VGPR

    // ---- prologue: X(0), B(0), X(1)  -> 24 outstanding ----
    xv[0][0] = gload_f32x4(prx);
    xv[0][1] = gload_f32x4(prx + 4);
    xv[0][2] = gload_f32x4(pix);
    xv[0][3] = gload_f32x4(pix + 4);
    #pragma unroll
    for (int nt = 0; nt < 4; ++nt) {
        bb[0][nt * 4 + 0] = gload_f16x8(bp0 + nt * 512);
        bb[0][nt * 4 + 1] = gload_f16x8(bp0 + nt * 512 + F_PSTRIDE);
        bb[0][nt * 4 + 2] = gload_f16x8(bp0 + nt * 512 + 2048);
        bb[0][nt * 4 + 3] = gload_f16x8(bp0 + nt * 512 + 2048 + F_PSTRIDE);
    }
    xv[1][0] = gload_f32x4(prx + 32);
    xv[1][1] = gload_f32x4(prx + 36);
    xv[1][2] = gload_f32x4(pix + 32);
    xv[1][3] = gload_f32x4(pix + 36);

    // ---- main loop (fully unrolled). Top-of-iter queue (oldest first):
    // X(p)4, B(p)16, X(p+1)4  (p<7)  |  X(7)4, B(7)16  (p==7)
    #pragma unroll 8
    for (int p = 0; p < 8; ++p) {
        const int s = p & 1, ns = s ^ 1;

        if (p < 7) { VMWAIT(20); } else { VMWAIT(16); }   // X(p) ready

        // transform X(p) -> fragments (in registers)
        f16x8 a1, a2, q1, q2;
        {
            const f32x4 vr0 = xv[s][0], vr1 = xv[s][1];
            const f32x4 vi0 = xv[s][2], vi1 = xv[s][3];
            #pragma unroll
            for (int i = 0; i < 4; ++i) {
                float rr = vr0[i], im = vi0[i];
                float amp = __builtin_amdgcn_sqrtf(fmaf(rr, rr, im * im));
                float ph  = fast_atan2f(im, rr);
                _Float16 hh, ll;
                fsplit2(amp, hh, ll); a1[i] = hh; a2[i] = ll;
                fsplit2(ph,  hh, ll); q1[i] = hh; q2[i] = ll;
                rr = vr1[i]; im = vi1[i];
                amp = __builtin_amdgcn_sqrtf(fmaf(rr, rr, im * im));
                ph  = fast_atan2f(im, rr);
                fsplit2(amp, hh, ll); a1[4 + i] = hh; a2[4 + i] = ll;
                fsplit2(ph,  hh, ll); q1[4 + i] = hh; q2[4 + i] = ll;
            }
        }

        if (p < 7) {
            // issue B(p+1)  -> 36 outstanding
            const _Float16* nb = bp0 + (size_t)(p + 1) * 4096;
            #pragma unroll
            for (int nt = 0; nt < 4; ++nt) {
                bb[ns][nt * 4 + 0] = gload_f16x8(nb + nt * 512);
                bb[ns][nt * 4 + 1] = gload_f16x8(nb + nt * 512 + F_PSTRIDE);
                bb[ns][nt * 4 + 2] = gload_f16x8(nb + nt * 512 + 2048);
                bb[ns][nt * 4 + 3] = gload_f16x8(nb + nt * 512 + 2048 + F_PSTRIDE);
            }
            VMWAIT(20);   // B(p) ready; X(p+1)+B(p+1)=20 stay in flight
        } else {
            VMWAIT(0);    // drain B(7)
        }

        // MFMA on chunk p
        #pragma unroll
        for (int nt = 0; nt < 4; ++nt) {
            const f16x8 b1a = bb[s][nt * 4 + 0];
            const f16x8 b2a = bb[s][nt * 4 + 1];
            const f16x8 b1p = bb[s][nt * 4 + 2];
            const f16x8 b2p = bb[s][nt * 4 + 3];
            accH[nt] = __builtin_amdgcn_mfma_f32_16x16x32_f16(a1, b1a, accH[nt], 0, 0, 0);
            accL[nt] = __builtin_amdgcn_mfma_f32_16x16x32_f16(a1, b2a, accL[nt], 0, 0, 0);
            accL[nt] = __builtin_amdgcn_mfma_f32_16x16x32_f16(a2, b1a, accL[nt], 0, 0, 0);
            accH[nt] = __builtin_amdgcn_mfma_f32_16x16x32_f16(q1, b1p, accH[nt], 0, 0, 0);
            accL[nt] = __builtin_amdgcn_mfma_f32_16x16x32_f16(q1, b2p, accL[nt], 0, 0, 0);
            accL[nt] = __builtin_amdgcn_mfma_f32_16x16x32_f16(q2, b1p, accL[nt], 0, 0, 0);
        }

        if (p < 6) {
            // issue X(p+2)  -> 24 outstanding (steady state)
            xv[s][0] = gload_f32x4(prx + (p + 2) * 32);
            xv[s][1] = gload_f32x4(prx + (p + 2) * 32 + 4);
            xv[s][2] = gload_f32x4(pix + (p + 2) * 32);
            xv[s][3] = gload_f32x4(pix + (p + 2) * 32 + 4);
        }
    }

    // write K-slice partials. D layout: col=lane&15, row=(lane>>4)*4+reg [m89]
    #pragma unroll
    for (int nt = 0; nt < 4; ++nt)
        #pragma unroll
        for (int r = 0; r < 4; ++r)
            scoreP[wv][fq * 4 + r][nt * 16 + fm] =
                fmaf(accL[nt][r], 4.8828125e-4f, accH[nt][r]);
    __syncthreads();   // the only block-wide sync

    // bias loaded AFTER the counted-vmcnt region (keeps loop counts exact)
    const float bv = bias[lane];

    // exact top-2 (tie-break lower index, matching lax.top_k); 2 tokens/wave
    #pragma unroll
    for (int rep = 0; rep < 2; ++rep) {
        const int tok = wv * 2 + rep;
        float v1 = bv;
        #pragma unroll
        for (int kq = 0; kq < 8; ++kq) v1 += scoreP[kq][tok][lane];
        float v2 = -INFINITY;
        int   i1 = lane, i2 = 64;
        #pragma unroll
        for (int off = 1; off < 64; off <<= 1) {
            const float ov1 = __shfl_xor(v1, off, 64);
            const int   oi1 = __shfl_xor(i1, off, 64);
            const float ov2 = __shfl_xor(v2, off, 64);
            const int   oi2 = __shfl_xor(i2, off, 64);
            const bool b1 = (ov1 > v1) || (ov1 == v1 && oi1 < i1);
            const float n1 = b1 ? ov1 : v1;  const int ni1 = b1 ? oi1 : i1;
            const float c1 = b1 ? v1  : ov1; const int ci1 = b1 ? i1  : oi1;
            const float c2 = b1 ? ov2 : v2;  const int ci2 = b1 ? oi2 : i2;
            const bool b2 = (c1 > c2) || (c1 == c2 && ci1 < ci2);
            v1 = n1; i1 = ni1;
            v2 = b2 ? c1 : c2; i2 = b2 ? ci1 : ci2;
        }
        if (lane == 0) {
            const int t = t0 + tok;
            const float z  = expf(v2 - v1);
            const float p1 = 1.0f / (1.0f + z);
            const float p2 = z / (1.0f + z);
            out[(size_t)t * 2 + 0] = p1;
            out[(size_t)t * 2 + 1] = p2;
            out[PROB_N + (size_t)t * 2 + 0] = (float)i1;
            out[PROB_N + (size_t)t * 2 + 1] = (float)i2;
        }
    }
}

extern "C" void kernel_launch(void* const* d_in, const int* in_sizes, int n_in,
                              void* d_out, int out_size, void* d_ws, size_t ws_size,
                              hipStream_t stream) {
    const float* xr = (const float*)d_in[0];
    const float* xi = (const float*)d_in[1];
    const float* W  = (const float*)d_in[2];
    const float* b  = (const float*)d_in[3];
    float* out = (float*)d_out;
    _Float16* F = (_Float16*)d_ws;   // 1 MB swizzled 2-plane fp16 W

    wsplit<<<128, 256, 0, stream>>>(W, F);
    gemm_topk<<<NTOK / TSTRIP, 512, 0, stream>>>(xr, xi, F, b, out);
}

// Round 8
// 170.259 us; speedup vs baseline: 1.1794x; 1.0203x over previous
//
#include <hip/hip_runtime.h>
#include <math.h>

#define NTOK 8192
#define DD   2048
#define EE   64
#define TSTRIP 32            // tokens per block (two MFMA m-tiles per wave)
#define PROB_N (NTOK*2)
// F layout: [plane:2][ck:128][nt:4][lane:64][j:8] fp16 = 1 MB
#define F_PSTRIDE (128*4*64*8)

typedef _Float16 f16x8 __attribute__((ext_vector_type(8)));
typedef _Float16 f16x4 __attribute__((ext_vector_type(4)));
typedef float    f32x4 __attribute__((ext_vector_type(4)));

// fast branchless atan2 (Cephes reduction + deg-7 odd minimax), ~3e-7 abs
__device__ __forceinline__ float fast_atan2f(float y, float x) {
    const float ax = __builtin_fabsf(x), ay = __builtin_fabsf(y);
    const float hi = fmaxf(ax, ay), lo = fminf(ax, ay);
    const bool  big = lo > 0.4142135679721832f * hi;       // tan(pi/8)
    const float num = big ? (lo - hi) : lo;
    const float den = big ? (lo + hi) : hi;
    float rc = __builtin_amdgcn_rcpf(den);
    rc = rc * fmaf(-den, rc, 2.0f);                        // 1 NR step
    const float z  = num * rc;
    const float z2 = z * z;
    float p = fmaf(z2, 8.05374449538e-2f, -1.38776856032e-1f);
    p = fmaf(z2, p, 1.99777106478e-1f);
    p = fmaf(z2, p, -3.33329491539e-1f);
    float r = fmaf(z * z2, p, z);
    r = r + (big ? 0.78539816339744830962f : 0.0f);
    r = (ay > ax) ? (1.57079632679489661923f - r) : r;
    r = (x < 0.0f) ? (3.14159265358979323846f - r) : r;
    return copysignf(r, y);
}

// fp16 2-split with scaled low plane: x ~= h1 + h2s*2^-11, err ~2^-24|x|
__device__ __forceinline__ void fsplit2(float x, _Float16& h1, _Float16& h2s) {
    const _Float16 a = (_Float16)x;                 // RNE, 11 bits
    h1 = a;
    h2s = (_Float16)((x - (float)a) * 2048.0f);     // next ~12 bits, normal-scaled
}

// Kernel 0: split W [4096][64] fp32 -> F fragment-order fp16 (2 planes, 1 MB)
__global__ __launch_bounds__(256) void wsplit(const float* __restrict__ W,
                                              _Float16* __restrict__ F) {
    const int g  = blockIdx.x * 256 + threadIdx.x;   // 32768 threads
    const int e  = g & 63;
    const int q  = g >> 6;          // 0..511
    const int d0 = q * 4;
    const int nt = e >> 4;
    const int lane = ((d0 & 31) >> 3) * 16 + (e & 15);
    const int j0 = d0 & 7;          // 0 or 4
    const int cka = 2 * (d0 >> 5);  // amp kstep; phase kstep = cka+1

    f16x4 a1, a2, p1, p2;
    #pragma unroll
    for (int i = 0; i < 4; ++i) {
        _Float16 h, l;
        fsplit2(W[(size_t)(d0 + i) * EE + e], h, l);      a1[i] = h; a2[i] = l;
        fsplit2(W[(size_t)(DD + d0 + i) * EE + e], h, l); p1[i] = h; p2[i] = l;
    }
    *(f16x4*)&F[((size_t)(0 * 128 + cka)     * 4 + nt) * 512 + lane * 8 + j0] = a1;
    *(f16x4*)&F[((size_t)(1 * 128 + cka)     * 4 + nt) * 512 + lane * 8 + j0] = a2;
    *(f16x4*)&F[((size_t)(0 * 128 + cka + 1) * 4 + nt) * 512 + lane * 8 + j0] = p1;
    *(f16x4*)&F[((size_t)(1 * 128 + cka + 1) * 4 + nt) * 512 + lane * 8 + j0] = p2;
}

// Kernel 1: barrier-free independent-wave streaming (R6 skeleton) with
// m-AMORTIZATION: each wave owns TWO m-tiles (rows fm and fm+16) over its
// 256-d K-slice, so every B fragment feeds 2 MFMAs -> B VMEM instructions
// and B L2 bytes halve (issue-bound regime per R0-R7 accounting; latency
// theories falsified by R5 occupancy test + R7 deep-pipeline test).
__global__ __launch_bounds__(512) void gemm_topk(
    const float* __restrict__ xr, const float* __restrict__ xi,
    const _Float16* __restrict__ F, const float* __restrict__ bias,
    float* __restrict__ out)
{
    __shared__ float scoreP[8][TSTRIP][EE + 1];   // 66.5 KB, padded (no 4-way conflict)

    const int tid = threadIdx.x;
    const int t0  = blockIdx.x * TSTRIP;
    const int wv = tid >> 6, lane = tid & 63;  // wv = K-slice 0..7
    const int fm = lane & 15, fq = lane >> 4;

    // x streams for the two m-tiles: rows t0+fm and t0+16+fm,
    // d = wv*256 + p*32 + fq*8 + (0..7)
    const float* prx0 = xr + (size_t)(t0 + fm) * DD + wv * 256 + fq * 8;
    const float* pix0 = xi + (size_t)(t0 + fm) * DD + wv * 256 + fq * 8;
    const float* prx1 = prx0 + 16 * DD;
    const float* pix1 = pix0 + 16 * DD;

    f32x4 accH0[4], accL0[4], accH1[4], accL1[4];   // per expert-tile nt
    #pragma unroll
    for (int nt = 0; nt < 4; ++nt) {
        accH0[nt] = (f32x4){0.f, 0.f, 0.f, 0.f};
        accL0[nt] = (f32x4){0.f, 0.f, 0.f, 0.f};
        accH1[nt] = (f32x4){0.f, 0.f, 0.f, 0.f};
        accL1[nt] = (f32x4){0.f, 0.f, 0.f, 0.f};
    }

    // transform 8 complex elements -> amp/phase 2-plane fragments (in regs)
    auto xform = [&](float4 r0, float4 r1, float4 i0, float4 i1,
                     f16x8& a1, f16x8& a2, f16x8& q1, f16x8& q2) {
        #pragma unroll
        for (int h = 0; h < 2; ++h) {
            const float4 vr = h ? r1 : r0;
            const float4 vi = h ? i1 : i0;
            const float ar[4] = {vr.x, vr.y, vr.z, vr.w};
            const float ai[4] = {vi.x, vi.y, vi.z, vi.w};
            #pragma unroll
            for (int i = 0; i < 4; ++i) {
                const float amp = __builtin_amdgcn_sqrtf(fmaf(ar[i], ar[i], ai[i] * ai[i]));
                const float ph  = fast_atan2f(ai[i], ar[i]);
                _Float16 hh, ll;
                fsplit2(amp, hh, ll); a1[h * 4 + i] = hh; a2[h * 4 + i] = ll;
                fsplit2(ph,  hh, ll); q1[h * 4 + i] = hh; q2[h * 4 + i] = ll;
            }
        }
    };

    #pragma unroll 2
    for (int p = 0; p < 8; ++p) {
        // m-tile 0 elements
        const float4 r00 = *(const float4*)(prx0 + p * 32);
        const float4 r01 = *(const float4*)(prx0 + p * 32 + 4);
        const float4 i00 = *(const float4*)(pix0 + p * 32);
        const float4 i01 = *(const float4*)(pix0 + p * 32 + 4);
        // m-tile 1 elements
        const float4 r10 = *(const float4*)(prx1 + p * 32);
        const float4 r11 = *(const float4*)(prx1 + p * 32 + 4);
        const float4 i10 = *(const float4*)(pix1 + p * 32);
        const float4 i11 = *(const float4*)(pix1 + p * 32 + 4);

        f16x8 a1_0, a2_0, q1_0, q2_0, a1_1, a2_1, q1_1, q2_1;
        xform(r00, r01, i00, i01, a1_0, a2_0, q1_0, q2_0);
        xform(r10, r11, i10, i11, a1_1, a2_1, q1_1, q2_1);

        // B fragments: amp ck = 2*(global 32-d group), phase ck = +1 (+2048 elems)
        const int ck = (wv * 8 + p) * 2;
        const _Float16* bp = F + ((size_t)ck * 4) * 512 + lane * 8;
        #pragma unroll
        for (int nt = 0; nt < 4; ++nt) {
            const _Float16* qp = bp + nt * 512;
            const f16x8 b1a = *(const f16x8*)(qp);
            const f16x8 b2a = *(const f16x8*)(qp + F_PSTRIDE);
            const f16x8 b1p = *(const f16x8*)(qp + 2048);
            const f16x8 b2p = *(const f16x8*)(qp + 2048 + F_PSTRIDE);
            // m-tile 0
            accH0[nt] = __builtin_amdgcn_mfma_f32_16x16x32_f16(a1_0, b1a, accH0[nt], 0, 0, 0);
            accL0[nt] = __builtin_amdgcn_mfma_f32_16x16x32_f16(a1_0, b2a, accL0[nt], 0, 0, 0);
            accL0[nt] = __builtin_amdgcn_mfma_f32_16x16x32_f16(a2_0, b1a, accL0[nt], 0, 0, 0);
            accH0[nt] = __builtin_amdgcn_mfma_f32_16x16x32_f16(q1_0, b1p, accH0[nt], 0, 0, 0);
            accL0[nt] = __builtin_amdgcn_mfma_f32_16x16x32_f16(q1_0, b2p, accL0[nt], 0, 0, 0);
            accL0[nt] = __builtin_amdgcn_mfma_f32_16x16x32_f16(q2_0, b1p, accL0[nt], 0, 0, 0);
            // m-tile 1 (same B fragments -- the amortization)
            accH1[nt] = __builtin_amdgcn_mfma_f32_16x16x32_f16(a1_1, b1a, accH1[nt], 0, 0, 0);
            accL1[nt] = __builtin_amdgcn_mfma_f32_16x16x32_f16(a1_1, b2a, accL1[nt], 0, 0, 0);
            accL1[nt] = __builtin_amdgcn_mfma_f32_16x16x32_f16(a2_1, b1a, accL1[nt], 0, 0, 0);
            accH1[nt] = __builtin_amdgcn_mfma_f32_16x16x32_f16(q1_1, b1p, accH1[nt], 0, 0, 0);
            accL1[nt] = __builtin_amdgcn_mfma_f32_16x16x32_f16(q1_1, b2p, accL1[nt], 0, 0, 0);
            accL1[nt] = __builtin_amdgcn_mfma_f32_16x16x32_f16(q2_1, b1p, accL1[nt], 0, 0, 0);
        }
    }

    // write K-slice partials. D layout: col=lane&15, row=(lane>>4)*4+reg [m89]
    #pragma unroll
    for (int nt = 0; nt < 4; ++nt)
        #pragma unroll
        for (int r = 0; r < 4; ++r) {
            scoreP[wv][fq * 4 + r][nt * 16 + fm] =
                fmaf(accL0[nt][r], 4.8828125e-4f, accH0[nt][r]);
            scoreP[wv][16 + fq * 4 + r][nt * 16 + fm] =
                fmaf(accL1[nt][r], 4.8828125e-4f, accH1[nt][r]);
        }
    __syncthreads();   // the only block-wide sync

    // exact top-2 (tie-break lower index, matching lax.top_k); 4 tokens/wave
    const float bv = bias[lane];
    #pragma unroll
    for (int rep = 0; rep < 4; ++rep) {
        const int tok = wv * 4 + rep;
        float v1 = bv;
        #pragma unroll
        for (int kq = 0; kq < 8; ++kq) v1 += scoreP[kq][tok][lane];
        float v2 = -INFINITY;
        int   i1 = lane, i2 = 64;
        #pragma unroll
        for (int off = 1; off < 64; off <<= 1) {
            const float ov1 = __shfl_xor(v1, off, 64);
            const int   oi1 = __shfl_xor(i1, off, 64);
            const float ov2 = __shfl_xor(v2, off, 64);
            const int   oi2 = __shfl_xor(i2, off, 64);
            const bool b1 = (ov1 > v1) || (ov1 == v1 && oi1 < i1);
            const float n1 = b1 ? ov1 : v1;  const int ni1 = b1 ? oi1 : i1;
            const float c1 = b1 ? v1  : ov1; const int ci1 = b1 ? i1  : oi1;
            const float c2 = b1 ? ov2 : v2;  const int ci2 = b1 ? oi2 : i2;
            const bool b2 = (c1 > c2) || (c1 == c2 && ci1 < ci2);
            v1 = n1; i1 = ni1;
            v2 = b2 ? c1 : c2; i2 = b2 ? ci1 : ci2;
        }
        if (lane == 0) {
            const int t = t0 + tok;
            const float z  = expf(v2 - v1);
            const float p1 = 1.0f / (1.0f + z);
            const float p2 = z / (1.0f + z);
            out[(size_t)t * 2 + 0] = p1;
            out[(size_t)t * 2 + 1] = p2;
            out[PROB_N + (size_t)t * 2 + 0] = (float)i1;
            out[PROB_N + (size_t)t * 2 + 1] = (float)i2;
        }
    }
}

extern "C" void kernel_launch(void* const* d_in, const int* in_sizes, int n_in,
                              void* d_out, int out_size, void* d_ws, size_t ws_size,
                              hipStream_t stream) {
    const float* xr = (const float*)d_in[0];
    const float* xi = (const float*)d_in[1];
    const float* W  = (const float*)d_in[2];
    const float* b  = (const float*)d_in[3];
    float* out = (float*)d_out;
    _Float16* F = (_Float16*)d_ws;   // 1 MB swizzled 2-plane fp16 W

    wsplit<<<128, 256, 0, stream>>>(W, F);
    gemm_topk<<<NTOK / TSTRIP, 512, 0, stream>>>(xr, xi, F, b, out);
}

// Round 9
// 170.158 us; speedup vs baseline: 1.1801x; 1.0006x over previous
//
#include <hip/hip_runtime.h>
#include <math.h>

#define NTOK 8192
#define DD   2048
#define EE   64
#define TSTRIP 16            // tokens per block (one MFMA m-tile)
#define PROB_N (NTOK*2)
// F layout: [plane:2][ck:128][nt:4][lane:64][j:8] fp16 = 1 MB
#define F_PSTRIDE (128*4*64*8)
#define XROW 516             // 512 cols + 4 pad floats: 2-way bank alias (free, m136), keeps 16B align

typedef _Float16 f16x8 __attribute__((ext_vector_type(8)));
typedef _Float16 f16x4 __attribute__((ext_vector_type(4)));
typedef float    f32x4 __attribute__((ext_vector_type(4)));

// fast branchless atan2 (Cephes reduction + deg-7 odd minimax), ~3e-7 abs
__device__ __forceinline__ float fast_atan2f(float y, float x) {
    const float ax = __builtin_fabsf(x), ay = __builtin_fabsf(y);
    const float hi = fmaxf(ax, ay), lo = fminf(ax, ay);
    const bool  big = lo > 0.4142135679721832f * hi;       // tan(pi/8)
    const float num = big ? (lo - hi) : lo;
    const float den = big ? (lo + hi) : hi;
    float rc = __builtin_amdgcn_rcpf(den);
    rc = rc * fmaf(-den, rc, 2.0f);                        // 1 NR step
    const float z  = num * rc;
    const float z2 = z * z;
    float p = fmaf(z2, 8.05374449538e-2f, -1.38776856032e-1f);
    p = fmaf(z2, p, 1.99777106478e-1f);
    p = fmaf(z2, p, -3.33329491539e-1f);
    float r = fmaf(z * z2, p, z);
    r = r + (big ? 0.78539816339744830962f : 0.0f);
    r = (ay > ax) ? (1.57079632679489661923f - r) : r;
    r = (x < 0.0f) ? (3.14159265358979323846f - r) : r;
    return copysignf(r, y);
}

// fp16 2-split with scaled low plane: x ~= h1 + h2s*2^-11, err ~2^-24|x|
__device__ __forceinline__ void fsplit2(float x, _Float16& h1, _Float16& h2s) {
    const _Float16 a = (_Float16)x;                 // RNE, 11 bits
    h1 = a;
    h2s = (_Float16)((x - (float)a) * 2048.0f);     // next ~12 bits, normal-scaled
}

// Kernel 0: split W [4096][64] fp32 -> F fragment-order fp16 (2 planes, 1 MB)
__global__ __launch_bounds__(256) void wsplit(const float* __restrict__ W,
                                              _Float16* __restrict__ F) {
    const int g  = blockIdx.x * 256 + threadIdx.x;   // 32768 threads
    const int e  = g & 63;
    const int q  = g >> 6;          // 0..511
    const int d0 = q * 4;
    const int nt = e >> 4;
    const int lane = ((d0 & 31) >> 3) * 16 + (e & 15);
    const int j0 = d0 & 7;          // 0 or 4
    const int cka = 2 * (d0 >> 5);  // amp kstep; phase kstep = cka+1

    f16x4 a1, a2, p1, p2;
    #pragma unroll
    for (int i = 0; i < 4; ++i) {
        _Float16 h, l;
        fsplit2(W[(size_t)(d0 + i) * EE + e], h, l);      a1[i] = h; a2[i] = l;
        fsplit2(W[(size_t)(DD + d0 + i) * EE + e], h, l); p1[i] = h; p2[i] = l;
    }
    *(f16x4*)&F[((size_t)(0 * 128 + cka)     * 4 + nt) * 512 + lane * 8 + j0] = a1;
    *(f16x4*)&F[((size_t)(1 * 128 + cka)     * 4 + nt) * 512 + lane * 8 + j0] = a2;
    *(f16x4*)&F[((size_t)(0 * 128 + cka + 1) * 4 + nt) * 512 + lane * 8 + j0] = p1;
    *(f16x4*)&F[((size_t)(1 * 128 + cka + 1) * 4 + nt) * 512 + lane * 8 + j0] = p2;
}

// Kernel 1: R6 compute core + IDEAL-COALESCED x staging. R0-R8 law:
// dur == FETCH/~1.05 TB/s in every round -> delivery-paced. The never-varied
// factor is the x access pattern (consecutive lanes were 8KB apart). Here all
// 512 threads stage x in m13-style contiguous 1KB-per-wave-instruction loads
// into LDS; waves ds_read_b128 their fragments (rows padded +4 -> 2-way bank
// alias, free). Wave wv owns groups {s*16+2wv(+1)} so all waves work each
// super-chunk. scoreP unions onto the staging buffer.
__global__ __launch_bounds__(512) void gemm_topk(
    const float* __restrict__ xr, const float* __restrict__ xi,
    const _Float16* __restrict__ F, const float* __restrict__ bias,
    float* __restrict__ out)
{
    // union: staging XR[16][516] + XI[16][516] (66048 B) / scoreP[8][16][64] (32 KB)
    __shared__ __align__(16) float SBUF[2 * 16 * XROW];
    float* XR = SBUF;                 // [16][XROW]
    float* XI = SBUF + 16 * XROW;     // [16][XROW]
    float* scoreP = SBUF;             // [8][16][64], reused after compute

    const int tid = threadIdx.x;
    const int t0  = blockIdx.x * TSTRIP;
    const int wv = tid >> 6, lane = tid & 63;
    const int fm = lane & 15, fq = lane >> 4;

    // staging thread mapping: slab k covers f32 offsets tid*4 + k*2048 of the
    // 16x512 super-chunk tile; 128 consecutive threads read 2KB contiguous.
    const int soff = tid * 4;
    const int srow = soff >> 9;           // 0..3 (slab k adds 4 rows each)
    const int scol = soff & 511;

    f32x4 accH[4], accL[4];
    #pragma unroll
    for (int nt = 0; nt < 4; ++nt) {
        accH[nt] = (f32x4){0.f, 0.f, 0.f, 0.f};
        accL[nt] = (f32x4){0.f, 0.f, 0.f, 0.f};
    }

    for (int s = 0; s < 4; ++s) {
        // ---- stage: contiguous global -> LDS (both arrays) ----
        const float* gxr = xr + (size_t)t0 * DD + s * 512;
        const float* gxi = xi + (size_t)t0 * DD + s * 512;
        #pragma unroll
        for (int k = 0; k < 4; ++k) {
            const int row = srow + k * 4;
            const float4 vr = *(const float4*)(gxr + (size_t)row * DD + scol);
            const float4 vi = *(const float4*)(gxi + (size_t)row * DD + scol);
            *(float4*)&XR[row * XROW + scol] = vr;
            *(float4*)&XI[row * XROW + scol] = vi;
        }
        __syncthreads();

        // ---- compute: 2 groups per wave in this super-chunk ----
        #pragma unroll
        for (int j = 0; j < 2; ++j) {
            const int cb = (2 * wv + j) * 32 + fq * 8;    // col in chunk
            const float4 r0 = *(const float4*)&XR[fm * XROW + cb];
            const float4 r1 = *(const float4*)&XR[fm * XROW + cb + 4];
            const float4 i0 = *(const float4*)&XI[fm * XROW + cb];
            const float4 i1 = *(const float4*)&XI[fm * XROW + cb + 4];

            // transform -> amp/phase 2-plane fragments (in registers)
            f16x8 a1, a2, q1, q2;
            #pragma unroll
            for (int h = 0; h < 2; ++h) {
                const float4 vr = h ? r1 : r0;
                const float4 vi = h ? i1 : i0;
                const float ar[4] = {vr.x, vr.y, vr.z, vr.w};
                const float ai[4] = {vi.x, vi.y, vi.z, vi.w};
                #pragma unroll
                for (int i = 0; i < 4; ++i) {
                    const float amp = __builtin_amdgcn_sqrtf(fmaf(ar[i], ar[i], ai[i] * ai[i]));
                    const float ph  = fast_atan2f(ai[i], ar[i]);
                    _Float16 hh, ll;
                    fsplit2(amp, hh, ll); a1[h * 4 + i] = hh; a2[h * 4 + i] = ll;
                    fsplit2(ph,  hh, ll); q1[h * 4 + i] = hh; q2[h * 4 + i] = ll;
                }
            }

            // B fragments for group g: amp ck=2g, phase ck=2g+1 (+2048 elems)
            const int g = s * 16 + 2 * wv + j;
            const _Float16* bp = F + ((size_t)(2 * g) * 4) * 512 + lane * 8;
            #pragma unroll
            for (int nt = 0; nt < 4; ++nt) {
                const _Float16* qp = bp + nt * 512;
                const f16x8 b1a = *(const f16x8*)(qp);
                const f16x8 b2a = *(const f16x8*)(qp + F_PSTRIDE);
                const f16x8 b1p = *(const f16x8*)(qp + 2048);
                const f16x8 b2p = *(const f16x8*)(qp + 2048 + F_PSTRIDE);
                accH[nt] = __builtin_amdgcn_mfma_f32_16x16x32_f16(a1, b1a, accH[nt], 0, 0, 0);
                accL[nt] = __builtin_amdgcn_mfma_f32_16x16x32_f16(a1, b2a, accL[nt], 0, 0, 0);
                accL[nt] = __builtin_amdgcn_mfma_f32_16x16x32_f16(a2, b1a, accL[nt], 0, 0, 0);
                accH[nt] = __builtin_amdgcn_mfma_f32_16x16x32_f16(q1, b1p, accH[nt], 0, 0, 0);
                accL[nt] = __builtin_amdgcn_mfma_f32_16x16x32_f16(q1, b2p, accL[nt], 0, 0, 0);
                accL[nt] = __builtin_amdgcn_mfma_f32_16x16x32_f16(q2, b1p, accL[nt], 0, 0, 0);
            }
        }
        __syncthreads();   // LDS reuse (next stage / scoreP union)
    }

    // write K-slice partials. D layout: col=lane&15, row=(lane>>4)*4+reg [m89]
    #pragma unroll
    for (int nt = 0; nt < 4; ++nt)
        #pragma unroll
        for (int r = 0; r < 4; ++r)
            scoreP[((wv * 16) + fq * 4 + r) * 64 + nt * 16 + fm] =
                fmaf(accL[nt][r], 4.8828125e-4f, accH[nt][r]);
    __syncthreads();

    // exact top-2 (tie-break lower index, matching lax.top_k); 2 tokens/wave
    const float bv = bias[lane];
    #pragma unroll
    for (int rep = 0; rep < 2; ++rep) {
        const int tok = wv * 2 + rep;
        float v1 = bv;
        #pragma unroll
        for (int kq = 0; kq < 8; ++kq) v1 += scoreP[(kq * 16 + tok) * 64 + lane];
        float v2 = -INFINITY;
        int   i1 = lane, i2 = 64;
        #pragma unroll
        for (int off = 1; off < 64; off <<= 1) {
            const float ov1 = __shfl_xor(v1, off, 64);
            const int   oi1 = __shfl_xor(i1, off, 64);
            const float ov2 = __shfl_xor(v2, off, 64);
            const int   oi2 = __shfl_xor(i2, off, 64);
            const bool b1 = (ov1 > v1) || (ov1 == v1 && oi1 < i1);
            const float n1 = b1 ? ov1 : v1;  const int ni1 = b1 ? oi1 : i1;
            const float c1 = b1 ? v1  : ov1; const int ci1 = b1 ? i1  : oi1;
            const float c2 = b1 ? ov2 : v2;  const int ci2 = b1 ? oi2 : i2;
            const bool b2 = (c1 > c2) || (c1 == c2 && ci1 < ci2);
            v1 = n1; i1 = ni1;
            v2 = b2 ? c1 : c2; i2 = b2 ? ci1 : ci2;
        }
        if (lane == 0) {
            const int t = t0 + tok;
            const float z  = expf(v2 - v1);
            const float p1 = 1.0f / (1.0f + z);
            const float p2 = z / (1.0f + z);
            out[(size_t)t * 2 + 0] = p1;
            out[(size_t)t * 2 + 1] = p2;
            out[PROB_N + (size_t)t * 2 + 0] = (float)i1;
            out[PROB_N + (size_t)t * 2 + 1] = (float)i2;
        }
    }
}

extern "C" void kernel_launch(void* const* d_in, const int* in_sizes, int n_in,
                              void* d_out, int out_size, void* d_ws, size_t ws_size,
                              hipStream_t stream) {
    const float* xr = (const float*)d_in[0];
    const float* xi = (const float*)d_in[1];
    const float* W  = (const float*)d_in[2];
    const float* b  = (const float*)d_in[3];
    float* out = (float*)d_out;
    _Float16* F = (_Float16*)d_ws;   // 1 MB swizzled 2-plane fp16 W

    wsplit<<<128, 256, 0, stream>>>(W, F);
    gemm_topk<<<NTOK / TSTRIP, 512, 0, stream>>>(xr, xi, F, b, out);
}